// Round 7
// baseline (295.217 us; speedup 1.0000x reference)
//
#include <hip/hip_runtime.h>

#define NB 2000000
static constexpr float EPSF = 1e-4f;
#define GRID_N 2048

// Fused single-kernel reduction (round 7):
//  - R5 established: same-address atomic wall (7813 all-at-once -> 105 us)
//    is gone with per-block partial stores; main kernel ~ memory floor.
//  - R6 established: LDS staging is neutral vs direct loads (per-wave the
//    direct float2/float4 loads are contiguous; aggregate line use is 100%).
//  - Remaining controllable cost is the second launch (~5-7 us incl. gap).
//    Fuse via last-block-done ticket: each block stores its partial
//    (agent-scope release), bumps a counter; the 2048 counter atomics are
//    STAGGERED across the kernel's execution so there is no drain tail.
//    The last block agent-scope-loads all partials and writes the output.
__global__ __launch_bounds__(256) void gcnl_fused(
    const float* __restrict__ pred_r,
    const float* __restrict__ pred_params,
    const float* __restrict__ pred_corr,
    const float* __restrict__ y_true,
    float* __restrict__ partial,
    unsigned int* __restrict__ counter,
    float* __restrict__ out)
{
    const int T = GRID_N * 256;
    float acc = 0.0f;

    for (int i = blockIdx.x * blockDim.x + threadIdx.x; i < NB; i += T) {
        const float2 rr = ((const float2*)pred_r)[i];
        const float2 pa = ((const float2*)pred_params)[3*i + 0];
        const float2 pb = ((const float2*)pred_params)[3*i + 1];
        const float2 pc = ((const float2*)pred_params)[3*i + 2];
        const float  c0 = pred_corr[3*i + 0];
        const float  c1 = pred_corr[3*i + 1];
        const float  c2 = pred_corr[3*i + 2];
        const float4 yt = ((const float4*)y_true)[i];

        const float r0 = rr.x, r1 = rr.y;
        const float pp0 = pa.x, pp1 = pa.y, pp2 = pb.x;
        const float pp3 = pb.y, pp4 = pc.x, pp5 = pc.y;
        const float r12 = c0, r13 = c1, r23 = c2;
        const float revert = yt.x, Rtop = yt.y, Top = yt.z, Close = yt.w;

        // s = exp(pp) => 1/s = exp(-pp), 0.5*log(s^2) = pp
        const float rtop  = __expf(pp0), is_rtop  = __expf(-pp1);
        const float top   = __expf(pp2), is_top   = __expf(-pp3);
        const float close = __expf(pp4), is_close = __expf(-pp5);

        const float d1 = (rtop  - Rtop ) * is_rtop;
        const float d2 = (top   - Top  ) * is_top;
        const float d3 = (close - Close) * is_close;

        // z = clip((x-u)/s, -3, 3): ndtr/erfinv round-trip collapses (eps-clip outside +-3)
        const float z1 = fminf(fmaxf(-d1, -3.0f), 3.0f);
        const float z2 = fminf(fmaxf(-d2, -3.0f), 3.0f);
        const float z3 = fminf(fmaxf(-d3, -3.0f), 3.0f);

        const float detR = 1.0f + 2.0f*r12*r13*r23 - r12*r12 - r13*r13 - r23*r23;
        const float inv_det = 1.0f / detR;
        const float i00 = (1.0f - r23*r23) * inv_det;
        const float i01 = (r13*r23 - r12) * inv_det;
        const float i02 = (r12*r23 - r13) * inv_det;
        const float i11 = (1.0f - r13*r13) * inv_det;
        const float i12 = (r12*r13 - r23) * inv_det;
        const float i22 = (1.0f - r12*r12) * inv_det;

        const float exp_term = 0.5f*((i00-1.0f)*z1*z1 + (i11-1.0f)*z2*z2 + (i22-1.0f)*z3*z3)
                             + (i01*z1*z2 + i02*z1*z3 + i12*z2*z3);
        const float c_gauss = 0.5f*__logf(fmaxf(detR, EPSF)) + exp_term;
        const float nll = 0.5f*(d1*d1 + d2*d2 + d3*d3) + (pp1 + pp3 + pp5);
        const float copula = revert * (c_gauss + nll);

        // cross-entropy: -logp[sel] = lse - r_sel
        const float m   = fmaxf(r0, r1);
        const float lse = m + __logf(1.0f + __expf(-fabsf(r0 - r1)));
        const float rsel = (revert != 0.0f) ? r1 : r0;

        acc += copula + (lse - rsel);
    }

    // block reduce: wave shuffle + LDS
    #pragma unroll
    for (int off = 32; off > 0; off >>= 1) acc += __shfl_down(acc, off, 64);

    __shared__ float warp_sums[4];
    __shared__ bool s_is_last;
    const int t = threadIdx.x;
    const int lane = t & 63;
    const int wid  = t >> 6;
    if (lane == 0) warp_sums[wid] = acc;
    __syncthreads();

    if (t == 0) {
        const float blocksum = warp_sums[0] + warp_sums[1] + warp_sums[2] + warp_sums[3];
        __hip_atomic_store(&partial[blockIdx.x], blocksum,
                           __ATOMIC_RELEASE, __HIP_MEMORY_SCOPE_AGENT);
        const unsigned ticket = __hip_atomic_fetch_add(counter, 1u,
                           __ATOMIC_ACQ_REL, __HIP_MEMORY_SCOPE_AGENT);
        s_is_last = (ticket == GRID_N - 1);
    }
    __syncthreads();

    if (s_is_last) {
        float a2 = 0.0f;
        for (int idx = t; idx < GRID_N; idx += 256)
            a2 += __hip_atomic_load(&partial[idx],
                                    __ATOMIC_RELAXED, __HIP_MEMORY_SCOPE_AGENT);
        #pragma unroll
        for (int off = 32; off > 0; off >>= 1) a2 += __shfl_down(a2, off, 64);
        if (lane == 0) warp_sums[wid] = a2;
        __syncthreads();
        if (t == 0) {
            const float s = warp_sums[0] + warp_sums[1] + warp_sums[2] + warp_sums[3];
            out[0] = s * (1.0f / (float)NB);
        }
    }
}

extern "C" void kernel_launch(void* const* d_in, const int* in_sizes, int n_in,
                              void* d_out, int out_size, void* d_ws, size_t ws_size,
                              hipStream_t stream) {
    const float* pred_r      = (const float*)d_in[0];
    const float* pred_params = (const float*)d_in[1];
    const float* pred_corr   = (const float*)d_in[2];
    const float* y_true      = (const float*)d_in[3];

    // ws layout: [0..4) counter, [256..256+GRID_N*4) partials (ws poisoned
    // to 0xAA each replay -> counter must be zeroed in-graph)
    unsigned int* counter = (unsigned int*)d_ws;
    float* partial = (float*)((char*)d_ws + 256);
    float* out = (float*)d_out;

    hipMemsetAsync(counter, 0, sizeof(unsigned int), stream);
    hipLaunchKernelGGL(gcnl_fused, dim3(GRID_N), dim3(256), 0, stream,
                       pred_r, pred_params, pred_corr, y_true,
                       partial, counter, out);
}

// Round 8
// 146.211 us; speedup vs baseline: 2.0191x; 2.0191x over previous
//
#include <hip/hip_runtime.h>

#define NB 2000000
static constexpr float EPSF = 1e-4f;
#define GRID_N 1024

// Round-7 finding: agent-scope RELEASE/ACQ_REL atomics on gfx950 emit
// per-XCD L2 writeback/invalidate (8 XCDs, non-coherent L2s) -> 2048 of
// them destroyed all cache locality (194 us, VALUBusy 3.5%). Plain
// relaxed device-scope atomicAdd has no fence cost, just ~13.4 ns/op
// serialized at the far point (R2-4: 7813 ops all queued = 105 us wall).
// This round: single kernel, 1024 blocks, ONE relaxed atomicAdd per block
// (13.7 us of queue work, overlapped with the ~25 us staggered main loop),
// no second launch, no fences.
__global__ __launch_bounds__(256) void gcnl_main(
    const float* __restrict__ pred_r,
    const float* __restrict__ pred_params,
    const float* __restrict__ pred_corr,
    const float* __restrict__ y_true,
    float* __restrict__ out)
{
    const int T = GRID_N * 256;  // 262144
    float acc = 0.0f;

    for (int i = blockIdx.x * blockDim.x + threadIdx.x; i < NB; i += T) {
        const float2 rr = ((const float2*)pred_r)[i];
        const float2 pa = ((const float2*)pred_params)[3*i + 0];
        const float2 pb = ((const float2*)pred_params)[3*i + 1];
        const float2 pc = ((const float2*)pred_params)[3*i + 2];
        const float  c0 = pred_corr[3*i + 0];
        const float  c1 = pred_corr[3*i + 1];
        const float  c2 = pred_corr[3*i + 2];
        const float4 yt = ((const float4*)y_true)[i];

        const float r0 = rr.x, r1 = rr.y;
        const float pp0 = pa.x, pp1 = pa.y, pp2 = pb.x;
        const float pp3 = pb.y, pp4 = pc.x, pp5 = pc.y;
        const float r12 = c0, r13 = c1, r23 = c2;
        const float revert = yt.x, Rtop = yt.y, Top = yt.z, Close = yt.w;

        // s = exp(pp) => 1/s = exp(-pp), 0.5*log(s^2) = pp
        const float rtop  = __expf(pp0), is_rtop  = __expf(-pp1);
        const float top   = __expf(pp2), is_top   = __expf(-pp3);
        const float close = __expf(pp4), is_close = __expf(-pp5);

        const float d1 = (rtop  - Rtop ) * is_rtop;
        const float d2 = (top   - Top  ) * is_top;
        const float d3 = (close - Close) * is_close;

        // z = clip((x-u)/s, -3, 3): ndtr/erfinv round-trip collapses (eps-clip outside +-3)
        const float z1 = fminf(fmaxf(-d1, -3.0f), 3.0f);
        const float z2 = fminf(fmaxf(-d2, -3.0f), 3.0f);
        const float z3 = fminf(fmaxf(-d3, -3.0f), 3.0f);

        const float detR = 1.0f + 2.0f*r12*r13*r23 - r12*r12 - r13*r13 - r23*r23;
        const float inv_det = 1.0f / detR;
        const float i00 = (1.0f - r23*r23) * inv_det;
        const float i01 = (r13*r23 - r12) * inv_det;
        const float i02 = (r12*r23 - r13) * inv_det;
        const float i11 = (1.0f - r13*r13) * inv_det;
        const float i12 = (r12*r13 - r23) * inv_det;
        const float i22 = (1.0f - r12*r12) * inv_det;

        const float exp_term = 0.5f*((i00-1.0f)*z1*z1 + (i11-1.0f)*z2*z2 + (i22-1.0f)*z3*z3)
                             + (i01*z1*z2 + i02*z1*z3 + i12*z2*z3);
        const float c_gauss = 0.5f*__logf(fmaxf(detR, EPSF)) + exp_term;
        const float nll = 0.5f*(d1*d1 + d2*d2 + d3*d3) + (pp1 + pp3 + pp5);
        const float copula = revert * (c_gauss + nll);

        // cross-entropy: -logp[sel] = lse - r_sel
        const float m   = fmaxf(r0, r1);
        const float lse = m + __logf(1.0f + __expf(-fabsf(r0 - r1)));
        const float rsel = (revert != 0.0f) ? r1 : r0;

        acc += copula + (lse - rsel);
    }

    // block reduce: wave shuffle + LDS, then ONE relaxed atomicAdd
    #pragma unroll
    for (int off = 32; off > 0; off >>= 1) acc += __shfl_down(acc, off, 64);

    __shared__ float warp_sums[4];
    const int t = threadIdx.x;
    const int lane = t & 63;
    const int wid  = t >> 6;
    if (lane == 0) warp_sums[wid] = acc;
    __syncthreads();
    if (t == 0) {
        const float s = warp_sums[0] + warp_sums[1] + warp_sums[2] + warp_sums[3];
        atomicAdd(out, s * (1.0f / (float)NB));   // plain relaxed, device scope
    }
}

extern "C" void kernel_launch(void* const* d_in, const int* in_sizes, int n_in,
                              void* d_out, int out_size, void* d_ws, size_t ws_size,
                              hipStream_t stream) {
    const float* pred_r      = (const float*)d_in[0];
    const float* pred_params = (const float*)d_in[1];
    const float* pred_corr   = (const float*)d_in[2];
    const float* y_true      = (const float*)d_in[3];
    float* out = (float*)d_out;

    // out is poisoned (0xAA) before every replay -> zero it in-graph
    hipMemsetAsync(out, 0, sizeof(float), stream);
    hipLaunchKernelGGL(gcnl_main, dim3(GRID_N), dim3(256), 0, stream,
                       pred_r, pred_params, pred_corr, y_true, out);
}

// Round 10
// 135.185 us; speedup vs baseline: 2.1838x; 1.0816x over previous
//
#include <hip/hip_runtime.h>

#define NB 2000000
static constexpr float EPSF = 1e-4f;

// R5 two-stage structure (best: 139.3 us total) + non-temporal loads.
// R8 learned: 7813 one-tile blocks beat 1024 grid-stride blocks (TLP).
// Fill-kernel calibration: streaming (non-allocating) accesses run 6.6 TB/s;
// our allocating reads ran 4.3 TB/s. NT loads take the streaming path.
// R9: __builtin_nontemporal_load needs clang native vectors, not
// HIP_vector_type -> use ext_vector_type shims.
typedef float vf2 __attribute__((ext_vector_type(2)));
typedef float vf4 __attribute__((ext_vector_type(4)));

__device__ __forceinline__ vf2 nt_load2(const float* p) {
    return __builtin_nontemporal_load((const vf2*)p);
}
__device__ __forceinline__ vf4 nt_load4(const float* p) {
    return __builtin_nontemporal_load((const vf4*)p);
}
__device__ __forceinline__ float nt_load1(const float* p) {
    return __builtin_nontemporal_load(p);
}

__global__ __launch_bounds__(256) void gcnl_main(
    const float* __restrict__ pred_r,
    const float* __restrict__ pred_params,
    const float* __restrict__ pred_corr,
    const float* __restrict__ y_true,
    float* __restrict__ partial)
{
    const int i = blockIdx.x * blockDim.x + threadIdx.x;
    float acc = 0.0f;

    if (i < NB) {
        const vf2 rr = nt_load2(pred_r + 2*i);
        const vf2 pa = nt_load2(pred_params + 6*i + 0);
        const vf2 pb = nt_load2(pred_params + 6*i + 2);
        const vf2 pc = nt_load2(pred_params + 6*i + 4);
        const float c0 = nt_load1(pred_corr + 3*i + 0);
        const float c1 = nt_load1(pred_corr + 3*i + 1);
        const float c2 = nt_load1(pred_corr + 3*i + 2);
        const vf4 yt = nt_load4(y_true + 4*i);

        const float r0 = rr.x, r1 = rr.y;
        const float pp0 = pa.x, pp1 = pa.y, pp2 = pb.x;
        const float pp3 = pb.y, pp4 = pc.x, pp5 = pc.y;
        const float r12 = c0, r13 = c1, r23 = c2;
        const float revert = yt.x, Rtop = yt.y, Top = yt.z, Close = yt.w;

        // s = exp(pp) => 1/s = exp(-pp), 0.5*log(s^2) = pp
        const float rtop  = __expf(pp0), is_rtop  = __expf(-pp1);
        const float top   = __expf(pp2), is_top   = __expf(-pp3);
        const float close = __expf(pp4), is_close = __expf(-pp5);

        const float d1 = (rtop  - Rtop ) * is_rtop;
        const float d2 = (top   - Top  ) * is_top;
        const float d3 = (close - Close) * is_close;

        // z = clip((x-u)/s, -3, 3): ndtr/erfinv round-trip collapses (eps-clip outside +-3)
        const float z1 = fminf(fmaxf(-d1, -3.0f), 3.0f);
        const float z2 = fminf(fmaxf(-d2, -3.0f), 3.0f);
        const float z3 = fminf(fmaxf(-d3, -3.0f), 3.0f);

        const float detR = 1.0f + 2.0f*r12*r13*r23 - r12*r12 - r13*r13 - r23*r23;
        const float inv_det = 1.0f / detR;
        const float i00 = (1.0f - r23*r23) * inv_det;
        const float i01 = (r13*r23 - r12) * inv_det;
        const float i02 = (r12*r23 - r13) * inv_det;
        const float i11 = (1.0f - r13*r13) * inv_det;
        const float i12 = (r12*r13 - r23) * inv_det;
        const float i22 = (1.0f - r12*r12) * inv_det;

        const float exp_term = 0.5f*((i00-1.0f)*z1*z1 + (i11-1.0f)*z2*z2 + (i22-1.0f)*z3*z3)
                             + (i01*z1*z2 + i02*z1*z3 + i12*z2*z3);
        const float c_gauss = 0.5f*__logf(fmaxf(detR, EPSF)) + exp_term;
        const float nll = 0.5f*(d1*d1 + d2*d2 + d3*d3) + (pp1 + pp3 + pp5);
        const float copula = revert * (c_gauss + nll);

        // cross-entropy: -logp[sel] = lse - r_sel
        const float m   = fmaxf(r0, r1);
        const float lse = m + __logf(1.0f + __expf(-fabsf(r0 - r1)));
        const float rsel = (revert != 0.0f) ? r1 : r0;

        acc = copula + (lse - rsel);
    }

    // block reduce: wave shuffle + LDS, plain store of partial
    #pragma unroll
    for (int off = 32; off > 0; off >>= 1) acc += __shfl_down(acc, off, 64);

    __shared__ float warp_sums[4];
    const int t = threadIdx.x;
    const int lane = t & 63;
    const int wid  = t >> 6;
    if (lane == 0) warp_sums[wid] = acc;
    __syncthreads();
    if (t == 0) {
        partial[blockIdx.x] = warp_sums[0] + warp_sums[1] + warp_sums[2] + warp_sums[3];
    }
}

// Stage 2: one block of 1024 threads sums n partials -> out = s / NB.
__global__ __launch_bounds__(1024) void gcnl_reduce(
    const float* __restrict__ partial, int n, float* __restrict__ out)
{
    const int t = threadIdx.x;
    float acc = 0.0f;
    for (int idx = t; idx < n; idx += 1024) acc += partial[idx];

    #pragma unroll
    for (int off = 32; off > 0; off >>= 1) acc += __shfl_down(acc, off, 64);

    __shared__ float warp_sums[16];
    const int lane = t & 63;
    const int wid  = t >> 6;
    if (lane == 0) warp_sums[wid] = acc;
    __syncthreads();
    if (t == 0) {
        float s = 0.0f;
        #pragma unroll
        for (int k = 0; k < 16; ++k) s += warp_sums[k];
        out[0] = s * (1.0f / (float)NB);
    }
}

extern "C" void kernel_launch(void* const* d_in, const int* in_sizes, int n_in,
                              void* d_out, int out_size, void* d_ws, size_t ws_size,
                              hipStream_t stream) {
    const float* pred_r      = (const float*)d_in[0];
    const float* pred_params = (const float*)d_in[1];
    const float* pred_corr   = (const float*)d_in[2];
    const float* y_true      = (const float*)d_in[3];
    float* partial = (float*)d_ws;   // fully overwritten each call
    float* out = (float*)d_out;

    const int block = 256;
    const int grid = (NB + block - 1) / block;  // 7813 blocks, 1 tile each
    hipLaunchKernelGGL(gcnl_main, dim3(grid), dim3(block), 0, stream,
                       pred_r, pred_params, pred_corr, y_true, partial);
    hipLaunchKernelGGL(gcnl_reduce, dim3(1), dim3(1024), 0, stream,
                       partial, grid, out);
}